// Round 9
// baseline (118.780 us; speedup 1.0000x reference)
//
#include <hip/hip_runtime.h>
#include <math.h>

#define NB 8
#define NQ 100
#define NQH 50
#define NCP1 3
#define NC 2
#define HIN 128
#define WIN 128
#define HOUT 512
#define WOUT 512
#define QSTR (HIN * WIN)
#define QBYTES (QSTR * 4)

#if __has_builtin(__builtin_amdgcn_exp2f)
#define EXP2F(x) __builtin_amdgcn_exp2f(x)
#else
#define EXP2F(x) exp2f(x)
#endif
#if __has_builtin(__builtin_amdgcn_rcpf)
#define RCPF(x) __builtin_amdgcn_rcpf(x)
#else
#define RCPF(x) (1.0f / (x))
#endif

__device__ __forceinline__ float bperm(int byteaddr, float v) {
  return __int_as_float(__builtin_amdgcn_ds_bpermute(byteaddr, __float_as_int(v)));
}

typedef float f32x4 __attribute__((ext_vector_type(4)));
typedef unsigned int u32x4 __attribute__((ext_vector_type(4)));

// R21 = R20 + XCD-batch swizzle + depth-8 vmem pipeline.
// R20 post-mortem killed the LDS-chain theory (gathers pipelined, nothing
// moved; wall also invariant to occupancy 54%->33%).  Survivor: the VMEM
// wait.  All variants share depth-5/vmcnt(8): per-iter stall >= eff-load-
// latency/5; measured 262 cyc/iter = compute ~110 + ~150 = ~900cy HBM
// latency / 5.  FETCH 83MB > 52MB input: old grid put all 8 batches of the
// same k on one XCD (linear%8 = k%8) -> every XCD streams all 52MB, loads
// miss L2.  Fixes:
//  (1) grid(8,128), b=blockIdx.x, k=blockIdx.y -> linear%8 = b -> each XCD
//      owns one batch's 6.5MB plane; neighbor k-blocks co-resident share
//      rows -> L2-hit latency (~250cy), FETCH -> ~55MB.
//  (2) prefetch depth 5 -> 8 (16 loads in flight, vmcnt(14)); stall =
//      latency/8.  Drain ladder vmcnt 14,12,...,0 at s=42..49.
// VGPR ~95 (8 stages x 8 + state) < 128 cap -> no spill (R19 hazard
// excluded).  Predict 44 -> 28-34us, FETCH -> 55-62MB, VALUBusy 55-65%.
__global__ __launch_bounds__(512, 4)
void m2f_fused(const float* __restrict__ cls,
               const float* __restrict__ masks,
               float* __restrict__ out) {
  const int b   = blockIdx.x;   // 0..7   (batch -> XCD under %8 round-robin)
  const int k   = blockIdx.y;   // 0..127 (row group)
  const int tid = threadIdx.x;  // 0..511

  __shared__ float  sigtab[4096];     // sigma(t_i), t_i = i/128 - 16
  __shared__ float2 pq[NQ];           // (p_class0, p_class1) per q
  __shared__ float  part[8][256];     // qh=1 partials: [acc][r*64+lane]

  // ---- sigma table: sig(t) = 1/(1+2^t), nearest-neighbor ----
#pragma unroll
  for (int j = 0; j < 8; ++j) {
    const int i = tid + j * 512;
    const float x = (float)i * 0.0078125f - 16.0f;
    sigtab[i] = RCPF(1.0f + EXP2F(x));
  }

  // ---- inline class softmax (keep first NC of NCP1) ----
  if (tid < NQ) {
    const float* cl = cls + (b * NQ + tid) * NCP1;
    float a0 = cl[0], a1 = cl[1], a2 = cl[2];
    float mx = fmaxf(a0, fmaxf(a1, a2));
    const float L2E = 1.4426950408889634f;
    float e0 = EXP2F((a0 - mx) * L2E);
    float e1 = EXP2F((a1 - mx) * L2E);
    float e2 = EXP2F((a2 - mx) * L2E);
    float inv = RCPF(e0 + e1 + e2);
    pq[tid] = make_float2(e0 * inv, e1 * inv);
  }
  __syncthreads();

  const int wave = tid >> 6;    // 0..7
  const int r    = wave & 3;    // output row phase (y = 4k+r)
  const int qh   = wave >> 2;   // q half: 0 -> q 0..49, 1 -> q 50..99
  const int lane = tid & 63;    // col group: x = 8*lane .. 8*lane+7
  const int q0   = qh * NQH;

  // clamped input rows + vertical weights.  t = -log2e * x (sigma(x) =
  // 1/(1+2^t)); index u = 128*t + 2048.5 (+0.5 = rounding bias).
  const int rlo = (r < 2) ? (k > 0 ? k - 1 : 0) : k;
  const int rhi = (r < 2) ? k : (k < HIN - 1 ? k + 1 : HIN - 1);
  const float NL2E128 = -1.4426950408889634f * 128.0f;
  const float wlo = ((r == 0) ? 0.375f : (r == 1) ? 0.125f
                   : (r == 2) ? 0.875f : 0.625f) * NL2E128;
  const float whi = ((r == 0) ? 0.625f : (r == 1) ? 0.875f
                   : (r == 2) ? 0.125f : 0.375f) * NL2E128;

  // buffer SRD over THIS batch's masks window: OOB (lane63 tail) reads 0.
  union { const float* p; unsigned long long u; } pn;
  pn.p = masks + (size_t)b * NQ * QSTR;
  u32x4 srd;
  srd.x = (unsigned int)pn.u;
  srd.y = (unsigned int)(pn.u >> 32) & 0xFFFFu;  // stride=0
  srd.z = (unsigned int)(NQ * QSTR * 4);         // num_records (bytes)
  srd.w = 0x00020000u;                           // raw dword access

  // 32-bit byte voffsets with the q-half folded in (max ~6.6MB, fits 32b)
  const int voffA = q0 * QBYTES + (rlo * WIN + 2 * lane) * 4;
  const int voffB = q0 * QBYTES + (rhi * WIN + 2 * lane) * 4;

  const int addrL = (lane - 1) << 2;
  const bool edgeL = (lane == 0);
  const bool edgeR = (lane == 63);

  // accumulators: Sum_q pd * sigma at the 4 eval points (x=class0,y=class1)
  float2 aS0 = make_float2(0.f, 0.f);
  float2 aSM = make_float2(0.f, 0.f);
  float2 aS1 = make_float2(0.f, 0.f);
  float2 aSR = make_float2(0.f, 0.f);   // sigma(mid(u1,u2)) = right-gap mid

  // depth-8 vmem pipeline + 1-deep sigma pipeline (sP = prev iter sigmas)
  f32x4 A0, B0, A1, B1, A2, B2, A3, B3, A4, B4, A5, B5, A6, B6, A7, B7;
  float sP0, sP1, sP2, sP3, sC0, sC1, sC2, sC3;

#define LOADSET(S, qrel)                                                  \
  do {                                                                    \
    asm volatile("buffer_load_dwordx4 %0, %2, %3, 0 offen\n\t"            \
                 "buffer_load_dwordx4 %1, %4, %3, 0 offen"                \
                 : "=&v"(A##S), "=&v"(B##S)                               \
                 : "v"(voffA + (qrel) * QBYTES), "s"(srd),                \
                   "v"(voffB + (qrel) * QBYTES));                         \
  } while (0)

  // wait until <= N loads outstanding (stage S's pair is the oldest)
#define WT(S, N)                                                          \
  asm volatile("s_waitcnt vmcnt(" #N ")" : "+v"(A##S), "+v"(B##S))

  // nearest-entry table sigmoid: u already = 128*t + 2048.5
#define SIG(u, sout)                                                      \
  do {                                                                    \
    float uc = fminf(fmaxf((u), 0.0f), 4095.0f);                          \
    sout = sigtab[(int)uc];                                               \
  } while (0)

  // issue phase: u-fmas + 4 table gathers (no consume)
#define GATHER(S)                                                         \
  do {                                                                    \
    float u0 = fmaf(wlo, A##S.x, fmaf(whi, B##S.x, 2048.5f));             \
    float u1 = fmaf(wlo, A##S.y, fmaf(whi, B##S.y, 2048.5f));             \
    float u2 = fmaf(wlo, A##S.z, fmaf(whi, B##S.z, 2048.5f));             \
    float um  = 0.5f * (u0 + u1);                                         \
    float umR = 0.5f * (u1 + u2);                                         \
    SIG(u0,  sC0);                                                        \
    SIG(um,  sC1);                                                        \
    SIG(u1,  sC2);                                                        \
    SIG(umR, sC3);                                                        \
  } while (0)

  // consume phase: accumulate PREVIOUS iteration's sigmas (pd read here,
  // lane-uniform LDS broadcast), then roll current -> prev
#define ACCROLL(qqprev)                                                   \
  do {                                                                    \
    const float2 pd = pq[qqprev];                                         \
    aS0.x = fmaf(pd.x, sP0, aS0.x);  aS0.y = fmaf(pd.y, sP0, aS0.y);      \
    aSM.x = fmaf(pd.x, sP1, aSM.x);  aSM.y = fmaf(pd.y, sP1, aSM.y);      \
    aS1.x = fmaf(pd.x, sP2, aS1.x);  aS1.y = fmaf(pd.y, sP2, aS1.y);      \
    aSR.x = fmaf(pd.x, sP3, aSR.x);  aSR.y = fmaf(pd.y, sP3, aSR.y);      \
    sP0 = sC0; sP1 = sC1; sP2 = sC2; sP3 = sC3;                           \
  } while (0)

#define PH(S, s)                                                          \
  do {                                                                    \
    WT(S, 14);                                                            \
    GATHER(S);                                                            \
    LOADSET(S, (s) + 8);                                                  \
    ACCROLL(q0 + (s) - 1);                                                \
  } while (0)

  LOADSET(0, 0); LOADSET(1, 1); LOADSET(2, 2); LOADSET(3, 3);
  LOADSET(4, 4); LOADSET(5, 5); LOADSET(6, 6); LOADSET(7, 7);

  // prologue s=0: gather, prime the sigma pipeline, refill stage 0 (q=8)
  WT(0, 14);
  GATHER(0);
  sP0 = sC0; sP1 = sC1; sP2 = sC2; sP3 = sC3;
  LOADSET(0, 8);

  // main: s = 1..40 (5 x 8); each PH accumulates s-1 and prefetches s+8
  for (int q = 1; q < 41; q += 8) {
    PH(1, q);     PH(2, q + 1); PH(3, q + 2); PH(4, q + 3);
    PH(5, q + 4); PH(6, q + 5); PH(7, q + 6); PH(0, q + 7);
  }
  PH(1, 41);   // loads q=49 (last set)

  // tail: s = 42..49, no more loads; drain vmcnt 14,12,...,0
  WT(2, 14); GATHER(2); ACCROLL(q0 + 41);
  WT(3, 12); GATHER(3); ACCROLL(q0 + 42);
  WT(4, 10); GATHER(4); ACCROLL(q0 + 43);
  WT(5, 8);  GATHER(5); ACCROLL(q0 + 44);
  WT(6, 6);  GATHER(6); ACCROLL(q0 + 45);
  WT(7, 4);  GATHER(7); ACCROLL(q0 + 46);
  WT(0, 2);  GATHER(0); ACCROLL(q0 + 47);
  WT(1, 0);  GATHER(1); ACCROLL(q0 + 48);
  // final consume: s=49's sigmas (now in sP)
  {
    const float2 pd = pq[q0 + 49];
    aS0.x = fmaf(pd.x, sP0, aS0.x);  aS0.y = fmaf(pd.y, sP0, aS0.y);
    aSM.x = fmaf(pd.x, sP1, aSM.x);  aSM.y = fmaf(pd.y, sP1, aSM.y);
    aS1.x = fmaf(pd.x, sP2, aS1.x);  aS1.y = fmaf(pd.y, sP2, aS1.y);
    aSR.x = fmaf(pd.x, sP3, aSR.x);  aSR.y = fmaf(pd.y, sP3, aSR.y);
  }

  // ---- combine q-halves through LDS (8 floats/col, conflict-free) ----
  const int col = r * 64 + lane;
  if (qh == 1) {
    part[0][col] = aS0.x;  part[1][col] = aS0.y;
    part[2][col] = aSM.x;  part[3][col] = aSM.y;
    part[4][col] = aS1.x;  part[5][col] = aS1.y;
    part[6][col] = aSR.x;  part[7][col] = aSR.y;
  }
  __syncthreads();
  if (qh == 0) {
    aS0.x += part[0][col];  aS0.y += part[1][col];
    aSM.x += part[2][col];  aSM.y += part[3][col];
    aS1.x += part[4][col];  aS1.y += part[5][col];
    aSR.x += part[6][col];  aSR.y += part[7][col];

    // SL = left neighbor's aSR (bperm of combined sum); lane 0: SL = S0.
    // SR = own aSR; lane 63: SR = S1 (discards the OOB-fed accumulator).
    float SLx_r = bperm(addrL, aSR.x);
    float SLy_r = bperm(addrL, aSR.y);
    float SLx = edgeL ? aS0.x : SLx_r;
    float SLy = edgeL ? aS0.y : SLy_r;
    float SRx = edgeR ? aS1.x : aSR.x;
    float SRy = edgeR ? aS1.y : aSR.y;

    // final half-gap interpolation (weights 0.75/0.25), once per wave
    float o0x = fmaf(0.25f, aS0.x, 0.75f * SLx);
    float o1x = fmaf(0.75f, aS0.x, 0.25f * SLx);
    float o2x = fmaf(0.25f, aSM.x, 0.75f * aS0.x);
    float o3x = fmaf(0.75f, aSM.x, 0.25f * aS0.x);
    float o4x = fmaf(0.25f, aS1.x, 0.75f * aSM.x);
    float o5x = fmaf(0.75f, aS1.x, 0.25f * aSM.x);
    float o6x = fmaf(0.25f, SRx,   0.75f * aS1.x);
    float o7x = fmaf(0.75f, SRx,   0.25f * aS1.x);
    float o0y = fmaf(0.25f, aS0.y, 0.75f * SLy);
    float o1y = fmaf(0.75f, aS0.y, 0.25f * SLy);
    float o2y = fmaf(0.25f, aSM.y, 0.75f * aS0.y);
    float o3y = fmaf(0.75f, aSM.y, 0.25f * aS0.y);
    float o4y = fmaf(0.25f, aS1.y, 0.75f * aSM.y);
    float o5y = fmaf(0.75f, aS1.y, 0.25f * aSM.y);
    float o6y = fmaf(0.25f, SRy,   0.75f * aS1.y);
    float o7y = fmaf(0.75f, SRy,   0.25f * aS1.y);

    const int y  = 4 * k + r;
    const int x0 = 8 * lane;
    float* o0 = out + (((size_t)b * NC + 0) * HOUT + y) * WOUT + x0;
    float* o1 = out + (((size_t)b * NC + 1) * HOUT + y) * WOUT + x0;
    *(float4*)o0       = make_float4(o0x, o1x, o2x, o3x);
    *(float4*)(o0 + 4) = make_float4(o4x, o5x, o6x, o7x);
    *(float4*)o1       = make_float4(o0y, o1y, o2y, o3y);
    *(float4*)(o1 + 4) = make_float4(o4y, o5y, o6y, o7y);
  }
}

extern "C" void kernel_launch(void* const* d_in, const int* in_sizes, int n_in,
                              void* d_out, int out_size, void* d_ws, size_t ws_size,
                              hipStream_t stream) {
  const float* cls   = (const float*)d_in[0];   // [8,100,3] fp32
  const float* masks = (const float*)d_in[1];   // [8,100,128,128] fp32
  float* out = (float*)d_out;                   // [8,2,512,512] fp32
  // grid(8,128): linear block id = b + 8*k -> id%8 = b -> one batch per XCD
  dim3 grid(NB, HIN);
  m2f_fused<<<grid, 512, 0, stream>>>(cls, masks, out);
}

// Round 11
// 113.406 us; speedup vs baseline: 1.0474x; 1.0474x over previous
//
#include <hip/hip_runtime.h>
#include <math.h>

#define NB 8
#define NQ 100
#define NQH 50
#define NCP1 3
#define NC 2
#define HIN 128
#define WIN 128
#define HOUT 512
#define WOUT 512
#define QSTR (HIN * WIN)
#define QBYTES (QSTR * 4)

#if __has_builtin(__builtin_amdgcn_exp2f)
#define EXP2F(x) __builtin_amdgcn_exp2f(x)
#else
#define EXP2F(x) exp2f(x)
#endif
#if __has_builtin(__builtin_amdgcn_rcpf)
#define RCPF(x) __builtin_amdgcn_rcpf(x)
#else
#define RCPF(x) (1.0f / (x))
#endif

__device__ __forceinline__ float bperm(int byteaddr, float v) {
  return __int_as_float(__builtin_amdgcn_ds_bpermute(byteaddr, __float_as_int(v)));
}

typedef unsigned int u32x4 __attribute__((ext_vector_type(4)));

// R23 = R22 resubmitted verbatim (R10's bench was an infra failure:
// "MI355X container failed twice" -- no compile/verify/timing happened).
// Theory unchanged from R22:
// R21 post-mortem: swizzle worked (FETCH 83->25.7MB, HBM 12%) but dur NULL
// at 44us -- latency theory dead.  Ledger: wall invariant to inner
// composition, occupancy, chain structure, latency class, prefetch depth.
// Station accounting per CU: LDS 18.8us, L1-return 21.3us (3200 wave-loads
// x 1KB / 64B/cyc), issue 14us; sum 54, wall 44 = 0.81 x sum (poor
// overlap, unmovable by scheduling).  Remaining lever: LOWER THE SUM.
// The dwordx4's .z/.w are waste (only u0,u1 used per row); revert to 8B
// dwordx2 and recover the halo via bperm(u1) INSIDE the pipelined GATHER
// (R17's halo + R20's pipeline; bperm latency hidden by issuing the 3
// halo-independent gathers first).  Stations: L1 21.3->10.7, LDS ~20,
// VALU ~14.5; sum 45; x0.81 -> ~36us predicted.
// If NULL again: declare practical ceiling (5 structural rewrites, all
// models exhausted).
__global__ __launch_bounds__(512, 4)
void m2f_fused(const float* __restrict__ cls,
               const float* __restrict__ masks,
               float* __restrict__ out) {
  const int b   = blockIdx.x;   // 0..7   (batch -> XCD under %8 round-robin)
  const int k   = blockIdx.y;   // 0..127 (row group)
  const int tid = threadIdx.x;  // 0..511

  __shared__ float  sigtab[4096];     // sigma(t_i), t_i = i/128 - 16
  __shared__ float2 pq[NQ];           // (p_class0, p_class1) per q
  __shared__ float  part[8][256];     // qh=1 partials: [acc][r*64+lane]

  // ---- sigma table: sig(t) = 1/(1+2^t), nearest-neighbor ----
#pragma unroll
  for (int j = 0; j < 8; ++j) {
    const int i = tid + j * 512;
    const float x = (float)i * 0.0078125f - 16.0f;
    sigtab[i] = RCPF(1.0f + EXP2F(x));
  }

  // ---- inline class softmax (keep first NC of NCP1) ----
  if (tid < NQ) {
    const float* cl = cls + (b * NQ + tid) * NCP1;
    float a0 = cl[0], a1 = cl[1], a2 = cl[2];
    float mx = fmaxf(a0, fmaxf(a1, a2));
    const float L2E = 1.4426950408889634f;
    float e0 = EXP2F((a0 - mx) * L2E);
    float e1 = EXP2F((a1 - mx) * L2E);
    float e2 = EXP2F((a2 - mx) * L2E);
    float inv = RCPF(e0 + e1 + e2);
    pq[tid] = make_float2(e0 * inv, e1 * inv);
  }
  __syncthreads();

  const int wave = tid >> 6;    // 0..7
  const int r    = wave & 3;    // output row phase (y = 4k+r)
  const int qh   = wave >> 2;   // q half: 0 -> q 0..49, 1 -> q 50..99
  const int lane = tid & 63;    // col group: x = 8*lane .. 8*lane+7
  const int q0   = qh * NQH;

  // clamped input rows + vertical weights.  t = -log2e * x (sigma(x) =
  // 1/(1+2^t)); index u = 128*t + 2048.5 (+0.5 = rounding bias).
  const int rlo = (r < 2) ? (k > 0 ? k - 1 : 0) : k;
  const int rhi = (r < 2) ? k : (k < HIN - 1 ? k + 1 : HIN - 1);
  const float NL2E128 = -1.4426950408889634f * 128.0f;
  const float wlo = ((r == 0) ? 0.375f : (r == 1) ? 0.125f
                   : (r == 2) ? 0.875f : 0.625f) * NL2E128;
  const float whi = ((r == 0) ? 0.625f : (r == 1) ? 0.875f
                   : (r == 2) ? 0.125f : 0.375f) * NL2E128;

  // buffer SRD over THIS batch's masks window (bounds-checked loads)
  union { const float* p; unsigned long long u; } pn;
  pn.p = masks + (size_t)b * NQ * QSTR;
  u32x4 srd;
  srd.x = (unsigned int)pn.u;
  srd.y = (unsigned int)(pn.u >> 32) & 0xFFFFu;  // stride=0
  srd.z = (unsigned int)(NQ * QSTR * 4);         // num_records (bytes)
  srd.w = 0x00020000u;                           // raw dword access

  // 32-bit byte voffsets with the q-half folded in (max ~6.6MB, fits 32b)
  const int voffA = q0 * QBYTES + (rlo * WIN + 2 * lane) * 4;
  const int voffB = q0 * QBYTES + (rhi * WIN + 2 * lane) * 4;

  const int addrL = (lane - 1) << 2;
  const int addrR = (lane + 1) << 2;
  const bool edgeL = (lane == 0);
  const bool edgeR = (lane == 63);

  // accumulators: Sum_q pd * sigma at {mid-left, u0, mid, u1}
  float2 aSL = make_float2(0.f, 0.f);
  float2 aS0 = make_float2(0.f, 0.f);
  float2 aSM = make_float2(0.f, 0.f);
  float2 aS1 = make_float2(0.f, 0.f);

  // depth-8 vmem pipeline (dwordx2 pairs) + 1-deep sigma pipeline
  float2 A0, B0, A1, B1, A2, B2, A3, B3, A4, B4, A5, B5, A6, B6, A7, B7;
  float sP0, sP1, sP2, sP3, sC0, sC1, sC2, sC3;

#define LOADSET(S, qrel)                                                  \
  do {                                                                    \
    asm volatile("buffer_load_dwordx2 %0, %2, %3, 0 offen\n\t"            \
                 "buffer_load_dwordx2 %1, %4, %3, 0 offen"                \
                 : "=&v"(A##S), "=&v"(B##S)                               \
                 : "v"(voffA + (qrel) * QBYTES), "s"(srd),                \
                   "v"(voffB + (qrel) * QBYTES));                         \
  } while (0)

  // wait until <= N loads outstanding (stage S's pair is the oldest)
#define WT(S, N)                                                          \
  asm volatile("s_waitcnt vmcnt(" #N ")" : "+v"(A##S), "+v"(B##S))

  // nearest-entry table sigmoid: u already = 128*t + 2048.5
#define SIG(u, sout)                                                      \
  do {                                                                    \
    float uc = fminf(fmaxf((u), 0.0f), 4095.0f);                          \
    sout = sigtab[(int)uc];                                               \
  } while (0)

  // issue phase: u-fmas + bperm halo + 4 table gathers (no consume).
  // bperm issued early; the 3 halo-independent gathers go first so the
  // bperm round-trip overlaps their issue (pipelined shadow covers rest).
#define GATHER(S)                                                         \
  do {                                                                    \
    float u0 = fmaf(wlo, A##S.x, fmaf(whi, B##S.x, 2048.5f));             \
    float u1 = fmaf(wlo, A##S.y, fmaf(whi, B##S.y, 2048.5f));             \
    float uLr = bperm(addrL, u1);                                         \
    float um = 0.5f * (u0 + u1);                                          \
    SIG(u0, sC1);                                                         \
    SIG(um, sC2);                                                         \
    SIG(u1, sC3);                                                         \
    float uL = edgeL ? u0 : uLr;                                          \
    float umL = 0.5f * (uL + u0);                                         \
    SIG(umL, sC0);                                                        \
  } while (0)

  // consume phase: accumulate PREVIOUS iteration's sigmas (pd read here,
  // lane-uniform LDS broadcast), then roll current -> prev
#define ACCROLL(qqprev)                                                   \
  do {                                                                    \
    const float2 pd = pq[qqprev];                                         \
    aSL.x = fmaf(pd.x, sP0, aSL.x);  aSL.y = fmaf(pd.y, sP0, aSL.y);      \
    aS0.x = fmaf(pd.x, sP1, aS0.x);  aS0.y = fmaf(pd.y, sP1, aS0.y);      \
    aSM.x = fmaf(pd.x, sP2, aSM.x);  aSM.y = fmaf(pd.y, sP2, aSM.y);      \
    aS1.x = fmaf(pd.x, sP3, aS1.x);  aS1.y = fmaf(pd.y, sP3, aS1.y);      \
    sP0 = sC0; sP1 = sC1; sP2 = sC2; sP3 = sC3;                           \
  } while (0)

#define PH(S, s)                                                          \
  do {                                                                    \
    WT(S, 14);                                                            \
    GATHER(S);                                                            \
    LOADSET(S, (s) + 8);                                                  \
    ACCROLL(q0 + (s) - 1);                                                \
  } while (0)

  LOADSET(0, 0); LOADSET(1, 1); LOADSET(2, 2); LOADSET(3, 3);
  LOADSET(4, 4); LOADSET(5, 5); LOADSET(6, 6); LOADSET(7, 7);

  // prologue s=0: gather, prime the sigma pipeline, refill stage 0 (q=8)
  WT(0, 14);
  GATHER(0);
  sP0 = sC0; sP1 = sC1; sP2 = sC2; sP3 = sC3;
  LOADSET(0, 8);

  // main: s = 1..40 (5 x 8); each PH accumulates s-1 and prefetches s+8
  for (int q = 1; q < 41; q += 8) {
    PH(1, q);     PH(2, q + 1); PH(3, q + 2); PH(4, q + 3);
    PH(5, q + 4); PH(6, q + 5); PH(7, q + 6); PH(0, q + 7);
  }
  PH(1, 41);   // loads q=49 (last set)

  // tail: s = 42..49, no more loads; drain vmcnt 14,12,...,0
  WT(2, 14); GATHER(2); ACCROLL(q0 + 41);
  WT(3, 12); GATHER(3); ACCROLL(q0 + 42);
  WT(4, 10); GATHER(4); ACCROLL(q0 + 43);
  WT(5, 8);  GATHER(5); ACCROLL(q0 + 44);
  WT(6, 6);  GATHER(6); ACCROLL(q0 + 45);
  WT(7, 4);  GATHER(7); ACCROLL(q0 + 46);
  WT(0, 2);  GATHER(0); ACCROLL(q0 + 47);
  WT(1, 0);  GATHER(1); ACCROLL(q0 + 48);
  // final consume: s=49's sigmas (now in sP)
  {
    const float2 pd = pq[q0 + 49];
    aSL.x = fmaf(pd.x, sP0, aSL.x);  aSL.y = fmaf(pd.y, sP0, aSL.y);
    aS0.x = fmaf(pd.x, sP1, aS0.x);  aS0.y = fmaf(pd.y, sP1, aS0.y);
    aSM.x = fmaf(pd.x, sP2, aSM.x);  aSM.y = fmaf(pd.y, sP2, aSM.y);
    aS1.x = fmaf(pd.x, sP3, aS1.x);  aS1.y = fmaf(pd.y, sP3, aS1.y);
  }

  // ---- combine q-halves through LDS (8 floats/col, conflict-free) ----
  const int col = r * 64 + lane;
  if (qh == 1) {
    part[0][col] = aSL.x;  part[1][col] = aSL.y;
    part[2][col] = aS0.x;  part[3][col] = aS0.y;
    part[4][col] = aSM.x;  part[5][col] = aSM.y;
    part[6][col] = aS1.x;  part[7][col] = aS1.y;
  }
  __syncthreads();
  if (qh == 0) {
    aSL.x += part[0][col];  aSL.y += part[1][col];
    aS0.x += part[2][col];  aS0.y += part[3][col];
    aSM.x += part[4][col];  aSM.y += part[5][col];
    aS1.x += part[6][col];  aS1.y += part[7][col];

    // SR = right neighbor's mid-left sum (bperm of combined aSL); lane 63:
    // SR = S1 (right-edge clamp)
    float SRx_r = bperm(addrR, aSL.x);
    float SRy_r = bperm(addrR, aSL.y);
    float SRx = edgeR ? aS1.x : SRx_r;
    float SRy = edgeR ? aS1.y : SRy_r;

    // final half-gap interpolation (weights 0.75/0.25), once per wave
    float o0x = fmaf(0.25f, aS0.x, 0.75f * aSL.x);
    float o1x = fmaf(0.75f, aS0.x, 0.25f * aSL.x);
    float o2x = fmaf(0.25f, aSM.x, 0.75f * aS0.x);
    float o3x = fmaf(0.75f, aSM.x, 0.25f * aS0.x);
    float o4x = fmaf(0.25f, aS1.x, 0.75f * aSM.x);
    float o5x = fmaf(0.75f, aS1.x, 0.25f * aSM.x);
    float o6x = fmaf(0.25f, SRx,   0.75f * aS1.x);
    float o7x = fmaf(0.75f, SRx,   0.25f * aS1.x);
    float o0y = fmaf(0.25f, aS0.y, 0.75f * aSL.y);
    float o1y = fmaf(0.75f, aS0.y, 0.25f * aSL.y);
    float o2y = fmaf(0.25f, aSM.y, 0.75f * aS0.y);
    float o3y = fmaf(0.75f, aSM.y, 0.25f * aS0.y);
    float o4y = fmaf(0.25f, aS1.y, 0.75f * aSM.y);
    float o5y = fmaf(0.75f, aS1.y, 0.25f * aSM.y);
    float o6y = fmaf(0.25f, SRy,   0.75f * aS1.y);
    float o7y = fmaf(0.75f, SRy,   0.25f * aS1.y);

    const int y  = 4 * k + r;
    const int x0 = 8 * lane;
    float* o0 = out + (((size_t)b * NC + 0) * HOUT + y) * WOUT + x0;
    float* o1 = out + (((size_t)b * NC + 1) * HOUT + y) * WOUT + x0;
    *(float4*)o0       = make_float4(o0x, o1x, o2x, o3x);
    *(float4*)(o0 + 4) = make_float4(o4x, o5x, o6x, o7x);
    *(float4*)o1       = make_float4(o0y, o1y, o2y, o3y);
    *(float4*)(o1 + 4) = make_float4(o4y, o5y, o6y, o7y);
  }
}

extern "C" void kernel_launch(void* const* d_in, const int* in_sizes, int n_in,
                              void* d_out, int out_size, void* d_ws, size_t ws_size,
                              hipStream_t stream) {
  const float* cls   = (const float*)d_in[0];   // [8,100,3] fp32
  const float* masks = (const float*)d_in[1];   // [8,100,128,128] fp32
  float* out = (float*)d_out;                   // [8,2,512,512] fp32
  // grid(8,128): linear block id = b + 8*k -> id%8 = b -> one batch per XCD
  dim3 grid(NB, HIN);
  m2f_fused<<<grid, 512, 0, stream>>>(cls, masks, out);
}